// Round 2
// baseline (491.480 us; speedup 1.0000x reference)
//
#include <hip/hip_runtime.h>
#include <hip/hip_bf16.h>
#include <stdint.h>

typedef unsigned short u16;
typedef __bf16 bf16_t;
typedef bf16_t bf16x8 __attribute__((ext_vector_type(8)));
typedef u16 u16x8 __attribute__((ext_vector_type(8)));
typedef u16 u16x4 __attribute__((ext_vector_type(4)));
typedef float f32x4 __attribute__((ext_vector_type(4)));

#define L2E 1.44269504088896f

__device__ __forceinline__ u16 f2bf(float f) {
  uint32_t u = __builtin_bit_cast(uint32_t, f);
  return (u16)((u + 0x7fffu + ((u >> 16) & 1u)) >> 16);
}
__device__ __forceinline__ float bf2f(u16 h) {
  return __builtin_bit_cast(float, (uint32_t)h << 16);
}
__device__ __forceinline__ void split2(float x, u16 &h, u16 &l) {
  h = f2bf(x);
  l = f2bf(x - bf2f(h));
}
__device__ __forceinline__ f32x4 mfma16(u16x8 a, u16x8 b, f32x4 c) {
  return __builtin_amdgcn_mfma_f32_16x16x32_bf16(
      __builtin_bit_cast(bf16x8, a), __builtin_bit_cast(bf16x8, b), c, 0, 0, 0);
}

// ---------------- mask normalize (handles uint8-bool or int32-bool storage) ---
__global__ void prep_mask_kernel(const unsigned char *__restrict__ mraw,
                                 float *__restrict__ bias) {
  __shared__ int flag;
  int t = threadIdx.x;
  if (t == 0) flag = 0;
  __syncthreads();
  int local = 0;
  for (int i = t; i < 8192; i += 256)
    if ((i & 3) && mraw[i]) local = 1;
  if (local) atomicOr(&flag, 1);
  __syncthreads();
  const bool bytes = (flag != 0); // nonzero byte at non-4-aligned offset => uint8 storage
  const int *mi = (const int *)mraw;
  for (int i = t; i < 8192; i += 256) {
    int m = bytes ? (int)mraw[i] : mi[i];
    bias[i] = m ? -1e30f : 0.0f;
  }
}

// ---------------- V transpose: vT[b][m][dd][j] = bf16(x2[b][j][m*256+dd]) ----
__global__ void transpose_v_kernel(const float *__restrict__ x2,
                                   u16 *__restrict__ vT) {
  __shared__ float tile[32][33];
  const int b = blockIdx.z, h0 = blockIdx.y * 32, j0 = blockIdx.x * 32;
  const int tx = threadIdx.x & 31, ty = threadIdx.x >> 5; // 32 x 8
#pragma unroll
  for (int rr = 0; rr < 32; rr += 8)
    tile[ty + rr][tx] = x2[((size_t)b * 1024 + j0 + ty + rr) * 1024 + h0 + tx];
  __syncthreads();
  const int mlev = h0 >> 8, dd0 = h0 & 255;
#pragma unroll
  for (int rr = 0; rr < 32; rr += 8) {
    int dd = dd0 + ty + rr;
    vT[((size_t)(b * 4 + mlev) * 256 + dd) * 1024 + j0 + tx] =
        f2bf(tile[tx][ty + rr]);
  }
}

// ---------------- split-bf16 projection GEMM: out = relu(A * W^T) [* fv] -----
// A[M][1024] f32, W[1024][1024] f32 (row-major [out][in]), out f32 [M][1024].
// 128x128 tile, BK=32, 4 waves (2x2 of 64x64), hi/lo split => 48 MFMA / K-step.
// LDS rows padded: 32 bf16 data + 8 pad = 40 u16 = 80 B (16B aligned, 2-way bank).
__device__ __forceinline__ void splitWrite8(u16 *baseH, u16 *baseL, uint32_t off,
                                            f32x4 x, f32x4 y) {
  u16x8 h, l;
#pragma unroll
  for (int e = 0; e < 4; ++e) {
    u16 hh, ll;
    split2(x[e], hh, ll); h[e] = hh; l[e] = ll;
    split2(y[e], hh, ll); h[4 + e] = hh; l[4 + e] = ll;
  }
  *(u16x8 *)((char *)baseH + off) = h;
  *(u16x8 *)((char *)baseL + off) = l;
}

__global__ __launch_bounds__(256, 2) void proj_kernel(
    const float *__restrict__ A, const float *__restrict__ W,
    const float *__restrict__ fv, float *__restrict__ out, int usefv) {
  __shared__ u16 Ah[128 * 40], Al[128 * 40], Bh[128 * 40], Bl[128 * 40];
  const int t = threadIdx.x;
  const int lane = t & 63, wid = t >> 6;
  const int l16 = lane & 15, g = lane >> 4;
  const int wr = wid >> 1, wc = wid & 1;
  const int bm = blockIdx.x, bn = blockIdx.y;

  f32x4 acc[4][4] = {};

  const int srow = t >> 1, sc0 = (t & 1) * 16; // stage: row, first col (f32 elems)
  const float *aSrc = A + (size_t)(bm * 128 + srow) * 1024 + sc0;
  const float *bSrc = W + (size_t)(bn * 128 + srow) * 1024 + sc0;
  const uint32_t off0 = srow * 80 + sc0 * 2;
  const uint32_t off1 = off0 + 16;

  for (int k0 = 0; k0 < 1024; k0 += 32) {
    f32x4 a0 = *(const f32x4 *)(aSrc + k0);
    f32x4 a1 = *(const f32x4 *)(aSrc + k0 + 4);
    f32x4 a2 = *(const f32x4 *)(aSrc + k0 + 8);
    f32x4 a3 = *(const f32x4 *)(aSrc + k0 + 12);
    f32x4 b0 = *(const f32x4 *)(bSrc + k0);
    f32x4 b1 = *(const f32x4 *)(bSrc + k0 + 4);
    f32x4 b2 = *(const f32x4 *)(bSrc + k0 + 8);
    f32x4 b3 = *(const f32x4 *)(bSrc + k0 + 12);
    __syncthreads(); // previous iteration's compute done
    splitWrite8(Ah, Al, off0, a0, a1);
    splitWrite8(Ah, Al, off1, a2, a3);
    splitWrite8(Bh, Bl, off0, b0, b1);
    splitWrite8(Bh, Bl, off1, b2, b3);
    __syncthreads(); // staging visible

    u16x8 afh[4], afl[4], bfh[4], bfl[4];
#pragma unroll
    for (int mf = 0; mf < 4; ++mf) {
      int r = wr * 64 + mf * 16 + l16;
      uint32_t off = r * 80 + g * 16;
      afh[mf] = *(const u16x8 *)((const char *)Ah + off);
      afl[mf] = *(const u16x8 *)((const char *)Al + off);
    }
#pragma unroll
    for (int nf = 0; nf < 4; ++nf) {
      int r = wc * 64 + nf * 16 + l16;
      uint32_t off = r * 80 + g * 16;
      bfh[nf] = *(const u16x8 *)((const char *)Bh + off);
      bfl[nf] = *(const u16x8 *)((const char *)Bl + off);
    }
#pragma unroll
    for (int mf = 0; mf < 4; ++mf)
#pragma unroll
      for (int nf = 0; nf < 4; ++nf) {
        acc[mf][nf] = mfma16(afh[mf], bfh[nf], acc[mf][nf]);
        acc[mf][nf] = mfma16(afh[mf], bfl[nf], acc[mf][nf]);
        acc[mf][nf] = mfma16(afl[mf], bfh[nf], acc[mf][nf]);
      }
  }

#pragma unroll
  for (int nf = 0; nf < 4; ++nf) {
    int col = bn * 128 + wc * 64 + nf * 16 + l16;
    float f = usefv ? fv[col] : 1.0f;
#pragma unroll
    for (int mf = 0; mf < 4; ++mf) {
      int row0 = bm * 128 + wr * 64 + mf * 16 + g * 4;
#pragma unroll
      for (int q = 0; q < 4; ++q) {
        float v = acc[mf][nf][q];
        v = v > 0.f ? v : 0.f;
        out[(size_t)(row0 + q) * 1024 + col] = v * f;
      }
    }
  }
}

// ---------------- fused flash attention per (i-tile, level, batch) ----------
// 4 waves x 16 Q rows; K-tile = 32; hi/lo QK (48 MFMA) + bf16 PV (16 MFMA).
__global__ __launch_bounds__(256, 2) void attn_kernel(
    const float *__restrict__ x1k, const float *__restrict__ x2k,
    const u16 *__restrict__ vT, const float *__restrict__ bias,
    float *__restrict__ out) {
  __shared__ u16 K2h[32 * 256], K2l[32 * 256]; // 16KB each, XOR-swizzled (16B gran)
  __shared__ u16 VTs[256 * 32];                // 16KB, XOR-swizzled (8B gran)
  __shared__ float biasS[1024];
  __shared__ u16 P[4][16 * 32]; // per-wave P tile, XOR-swizzled (8B gran)

  const int t = threadIdx.x;
  const int lane = t & 63, wid = t >> 6;
  const int l16 = lane & 15, g = lane >> 4;
  const int it = blockIdx.x, m = blockIdx.y, b = blockIdx.z;

  for (int j = t; j < 1024; j += 256) biasS[j] = bias[b * 1024 + j];

  // hoist Q (hi/lo) into registers: A-frag rows = l16, k = dk*32 + g*8 + e
  const int qrow = it * 64 + wid * 16 + l16;
  const float *qsrc = x1k + ((size_t)b * 1024 + qrow) * 1024 + m * 256;
  u16x8 Qh[8], Ql[8];
#pragma unroll
  for (int dk = 0; dk < 8; ++dk) {
    f32x4 v0 = *(const f32x4 *)(qsrc + dk * 32 + g * 8);
    f32x4 v1 = *(const f32x4 *)(qsrc + dk * 32 + g * 8 + 4);
    u16x8 h, l;
#pragma unroll
    for (int e = 0; e < 4; ++e) {
      u16 hh, ll;
      split2(v0[e], hh, ll); h[e] = hh; l[e] = ll;
      split2(v1[e], hh, ll); h[4 + e] = hh; l[4 + e] = ll;
    }
    Qh[dk] = h; Ql[dk] = l;
  }

  f32x4 acc[16] = {};
  float mrow[4] = {-1e30f, -1e30f, -1e30f, -1e30f};
  float lrow[4] = {0.f, 0.f, 0.f, 0.f};

  const int sj = t >> 3, sc0 = (t & 7) * 32; // K2 staging: 8 thr/row, 32 f32 each
  const float *k2src = x2k + ((size_t)b * 1024 + sj) * 1024 + m * 256 + sc0;
  const int sdd = t; // VT staging: 1 row (32 u16) per thread
  const u16 *vtsrc = vT + ((size_t)((b * 4 + m) * 256 + sdd)) * 1024;

  for (int jt = 0; jt < 32; ++jt) {
    const int j0 = jt * 32;
    __syncthreads(); // prev compute reads done
    { // stage K2 (split f32 -> hi/lo bf16)
      const float *s = k2src + (size_t)j0 * 1024;
      const uint32_t kxo = ((sj & 7) << 4);
#pragma unroll
      for (int q = 0; q < 4; ++q) {
        f32x4 v0 = *(const f32x4 *)(s + q * 8);
        f32x4 v1 = *(const f32x4 *)(s + q * 8 + 4);
        uint32_t off = sj * 512 + (((sc0 + q * 8) * 2) ^ kxo);
        splitWrite8(K2h, K2l, off, v0, v1);
      }
    }
    { // stage VT (already bf16)
      const u16 *s = vtsrc + j0;
      const uint32_t vxo = ((sdd & 7) << 3);
#pragma unroll
      for (int q = 0; q < 4; ++q) {
        u16x8 v = *(const u16x8 *)(s + q * 8);
        u16x4 lo = {v[0], v[1], v[2], v[3]};
        u16x4 hi = {v[4], v[5], v[6], v[7]};
        uint32_t base = sdd * 64 + q * 16;
        *(u16x4 *)((char *)VTs + (base ^ vxo)) = lo;
        *(u16x4 *)((char *)VTs + ((base + 8) ^ vxo)) = hi;
      }
    }
    __syncthreads(); // staging visible

    // QK^T (hi/lo): S[i][j], D rows i=g*4+r, cols j=l16 (+16 for sub1)
    f32x4 s0 = {0.f, 0.f, 0.f, 0.f}, s1 = {0.f, 0.f, 0.f, 0.f};
    {
      const int j = l16;
      const uint32_t kxo = ((j & 7) << 4);
      const char *rowH = (const char *)K2h + j * 512;
      const char *rowL = (const char *)K2l + j * 512;
#pragma unroll
      for (int dk = 0; dk < 8; ++dk) {
        uint32_t off = (uint32_t)(dk * 64 + g * 16) ^ kxo;
        u16x8 kh = *(const u16x8 *)(rowH + off);
        u16x8 kl = *(const u16x8 *)(rowL + off);
        s0 = mfma16(Qh[dk], kh, s0);
        s0 = mfma16(Qh[dk], kl, s0);
        s0 = mfma16(Ql[dk], kh, s0);
      }
    }
    {
      const int j = 16 + l16;
      const uint32_t kxo = ((j & 7) << 4);
      const char *rowH = (const char *)K2h + j * 512;
      const char *rowL = (const char *)K2l + j * 512;
#pragma unroll
      for (int dk = 0; dk < 8; ++dk) {
        uint32_t off = (uint32_t)(dk * 64 + g * 16) ^ kxo;
        u16x8 kh = *(const u16x8 *)(rowH + off);
        u16x8 kl = *(const u16x8 *)(rowL + off);
        s1 = mfma16(Qh[dk], kh, s1);
        s1 = mfma16(Qh[dk], kl, s1);
        s1 = mfma16(Ql[dk], kh, s1);
      }
    }

    // online softmax (rows replicated across the 16 lanes of each g-group)
    float sv[2][4];
    const float bj0 = biasS[j0 + l16], bj1 = biasS[j0 + 16 + l16];
#pragma unroll
    for (int r = 0; r < 4; ++r) { sv[0][r] = s0[r] + bj0; sv[1][r] = s1[r] + bj1; }
    float tm[4];
#pragma unroll
    for (int r = 0; r < 4; ++r) tm[r] = fmaxf(sv[0][r], sv[1][r]);
#pragma unroll
    for (int d = 1; d < 16; d <<= 1)
#pragma unroll
      for (int r = 0; r < 4; ++r) tm[r] = fmaxf(tm[r], __shfl_xor(tm[r], d, 64));
    float sc[4];
#pragma unroll
    for (int r = 0; r < 4; ++r) {
      float nm = fmaxf(mrow[r], tm[r]);
      sc[r] = exp2f((mrow[r] - nm) * L2E);
      mrow[r] = nm;
    }
    float p[2][4], rs[4];
#pragma unroll
    for (int r = 0; r < 4; ++r) {
      p[0][r] = exp2f((sv[0][r] - mrow[r]) * L2E);
      p[1][r] = exp2f((sv[1][r] - mrow[r]) * L2E);
      rs[r] = p[0][r] + p[1][r];
    }
#pragma unroll
    for (int d = 1; d < 16; d <<= 1)
#pragma unroll
      for (int r = 0; r < 4; ++r) rs[r] += __shfl_xor(rs[r], d, 64);
#pragma unroll
    for (int r = 0; r < 4; ++r) lrow[r] = lrow[r] * sc[r] + rs[r];
#pragma unroll
    for (int nf = 0; nf < 16; ++nf)
#pragma unroll
      for (int r = 0; r < 4; ++r) acc[nf][r] *= sc[r];

    // P -> per-wave LDS (bf16), then PV
    u16 *Pw = &P[wid][0];
#pragma unroll
    for (int sub = 0; sub < 2; ++sub)
#pragma unroll
      for (int r = 0; r < 4; ++r) {
        int il = g * 4 + r, jl = sub * 16 + l16;
        *(u16 *)((char *)Pw + il * 64 + ((jl * 2) ^ ((il & 7) << 3))) =
            f2bf(p[sub][r]);
      }
    u16x8 pa;
    {
      const uint32_t xo2 = ((l16 & 7) << 3);
      const uint32_t base = l16 * 64 + g * 16;
      u16x4 a0 = *(const u16x4 *)((const char *)Pw + (base ^ xo2));
      u16x4 a1 = *(const u16x4 *)((const char *)Pw + ((base + 8) ^ xo2));
      pa = __builtin_shufflevector(a0, a1, 0, 1, 2, 3, 4, 5, 6, 7);
    }
#pragma unroll
    for (int nf = 0; nf < 16; ++nf) {
      int dd = nf * 16 + l16;
      const uint32_t xo3 = ((dd & 7) << 3);
      const uint32_t base = dd * 64 + g * 16;
      u16x4 b0 = *(const u16x4 *)((const char *)VTs + (base ^ xo3));
      u16x4 b1 = *(const u16x4 *)((const char *)VTs + ((base + 8) ^ xo3));
      u16x8 bb = __builtin_shufflevector(b0, b1, 0, 1, 2, 3, 4, 5, 6, 7);
      acc[nf] = mfma16(pa, bb, acc[nf]);
    }
  }

  float inv[4];
#pragma unroll
  for (int r = 0; r < 4; ++r) inv[r] = 1.0f / lrow[r];
#pragma unroll
  for (int nf = 0; nf < 16; ++nf) {
    int col = m * 256 + nf * 16 + l16;
#pragma unroll
    for (int r = 0; r < 4; ++r) {
      int row = it * 64 + wid * 16 + g * 4 + r;
      out[((size_t)b * 1024 + row) * 1024 + col] = acc[nf][r] * inv[r];
    }
  }
}

// ---------------- launch ----------------------------------------------------
extern "C" void kernel_launch(void *const *d_in, const int *in_sizes, int n_in,
                              void *d_out, int out_size, void *d_ws,
                              size_t ws_size, hipStream_t stream) {
  const float *x1_att = (const float *)d_in[0];
  const float *x2_att = (const float *)d_in[1];
  const float *x2 = (const float *)d_in[2];
  const unsigned char *mask = (const unsigned char *)d_in[3];
  const float *W = (const float *)d_in[4];
  const float *fv = (const float *)d_in[5];
  float *out = (float *)d_out;

  char *ws = (char *)d_ws;
  float *x1k = (float *)ws;                  // 8192*1024*4 = 33554432 B
  float *x2k = (float *)(ws + 33554432);     // 33554432 B
  u16 *vT = (u16 *)(ws + 67108864);          // 8*4*256*1024*2 = 16777216 B
  float *bias = (float *)(ws + 83886080);    // 32768 B  (total ~80 MB)

  prep_mask_kernel<<<dim3(1), dim3(256), 0, stream>>>(mask, bias);
  transpose_v_kernel<<<dim3(32, 32, 8), dim3(256), 0, stream>>>(x2, vT);
  proj_kernel<<<dim3(64, 8), dim3(256), 0, stream>>>(x1_att, W, fv, x1k, 0);
  proj_kernel<<<dim3(64, 8), dim3(256), 0, stream>>>(x2_att, W, fv, x2k, 1);
  attn_kernel<<<dim3(16, 4, 8), dim3(256), 0, stream>>>(x1k, x2k, vT, bias, out);
}

// Round 3
// 442.928 us; speedup vs baseline: 1.1096x; 1.1096x over previous
//
#include <hip/hip_runtime.h>
#include <hip/hip_bf16.h>
#include <stdint.h>

typedef unsigned short u16;
typedef __bf16 bf16_t;
typedef bf16_t bf16x8 __attribute__((ext_vector_type(8)));
typedef u16 u16x8 __attribute__((ext_vector_type(8)));
typedef u16 u16x4 __attribute__((ext_vector_type(4)));
typedef float f32x4 __attribute__((ext_vector_type(4)));

#define L2E 1.44269504088896f

__device__ __forceinline__ u16 f2bf(float f) {
  uint32_t u = __builtin_bit_cast(uint32_t, f);
  return (u16)((u + 0x7fffu + ((u >> 16) & 1u)) >> 16);
}
__device__ __forceinline__ float bf2f(u16 h) {
  return __builtin_bit_cast(float, (uint32_t)h << 16);
}
__device__ __forceinline__ void split2(float x, u16 &h, u16 &l) {
  h = f2bf(x);
  l = f2bf(x - bf2f(h));
}
__device__ __forceinline__ f32x4 mfma16(u16x8 a, u16x8 b, f32x4 c) {
  return __builtin_amdgcn_mfma_f32_16x16x32_bf16(
      __builtin_bit_cast(bf16x8, a), __builtin_bit_cast(bf16x8, b), c, 0, 0, 0);
}

// ---------------- mask normalize (handles uint8-bool or int32-bool storage) ---
__global__ void prep_mask_kernel(const unsigned char *__restrict__ mraw,
                                 float *__restrict__ bias) {
  __shared__ int flag;
  int t = threadIdx.x;
  if (t == 0) flag = 0;
  __syncthreads();
  int local = 0;
  for (int i = t; i < 8192; i += 256)
    if ((i & 3) && mraw[i]) local = 1;
  if (local) atomicOr(&flag, 1);
  __syncthreads();
  const bool bytes = (flag != 0);
  const int *mi = (const int *)mraw;
  for (int i = t; i < 8192; i += 256) {
    int m = bytes ? (int)mraw[i] : mi[i];
    bias[i] = m ? -1e30f : 0.0f;
  }
}

// ---------------- V transpose: vT[b][m][dd][j] = bf16(x2[b][j][m*256+dd]) ----
__global__ void transpose_v_kernel(const float *__restrict__ x2,
                                   u16 *__restrict__ vT) {
  __shared__ float tile[32][33];
  const int b = blockIdx.z, h0 = blockIdx.y * 32, j0 = blockIdx.x * 32;
  const int tx = threadIdx.x & 31, ty = threadIdx.x >> 5; // 32 x 8
#pragma unroll
  for (int rr = 0; rr < 32; rr += 8)
    tile[ty + rr][tx] = x2[((size_t)b * 1024 + j0 + ty + rr) * 1024 + h0 + tx];
  __syncthreads();
  const int mlev = h0 >> 8, dd0 = h0 & 255;
#pragma unroll
  for (int rr = 0; rr < 32; rr += 8) {
    int dd = dd0 + ty + rr;
    vT[((size_t)(b * 4 + mlev) * 256 + dd) * 1024 + j0 + tx] =
        f2bf(tile[tx][ty + rr]);
  }
}

// ---------------- split-bf16 projection GEMM: relu(A*W^T)[*fv] -> hi/lo bf16 -
// A[M][1024] f32, W[1024][1024] f32. 128x128 tile, BK=32, 4 waves, 48 MFMA/K.
// LDS rows: 32 bf16 + 8 pad = 80 B. T14 register prefetch of next K-tile.
__device__ __forceinline__ void splitWrite8(u16 *baseH, u16 *baseL, uint32_t off,
                                            f32x4 x, f32x4 y) {
  u16x8 h, l;
#pragma unroll
  for (int e = 0; e < 4; ++e) {
    u16 hh, ll;
    split2(x[e], hh, ll); h[e] = hh; l[e] = ll;
    split2(y[e], hh, ll); h[4 + e] = hh; l[4 + e] = ll;
  }
  *(u16x8 *)((char *)baseH + off) = h;
  *(u16x8 *)((char *)baseL + off) = l;
}

__global__ __launch_bounds__(256, 2) void proj_kernel(
    const float *__restrict__ A, const float *__restrict__ W,
    const float *__restrict__ fv, u16 *__restrict__ outh,
    u16 *__restrict__ outl, int usefv) {
  __shared__ u16 Ah[128 * 40], Al[128 * 40], Bh[128 * 40], Bl[128 * 40];
  const int t = threadIdx.x;
  const int lane = t & 63, wid = t >> 6;
  const int l16 = lane & 15, g = lane >> 4;
  const int wr = wid >> 1, wc = wid & 1;
  const int bm = blockIdx.x, bn = blockIdx.y;

  f32x4 acc[4][4] = {};

  const int srow = t >> 1, sc0 = (t & 1) * 16;
  const float *aSrc = A + (size_t)(bm * 128 + srow) * 1024 + sc0;
  const float *bSrc = W + (size_t)(bn * 128 + srow) * 1024 + sc0;
  const uint32_t off0 = srow * 80 + sc0 * 2;
  const uint32_t off1 = off0 + 16;

  f32x4 ra0 = *(const f32x4 *)(aSrc), ra1 = *(const f32x4 *)(aSrc + 4);
  f32x4 ra2 = *(const f32x4 *)(aSrc + 8), ra3 = *(const f32x4 *)(aSrc + 12);
  f32x4 rb0 = *(const f32x4 *)(bSrc), rb1 = *(const f32x4 *)(bSrc + 4);
  f32x4 rb2 = *(const f32x4 *)(bSrc + 8), rb3 = *(const f32x4 *)(bSrc + 12);

  for (int k0 = 0; k0 < 1024; k0 += 32) {
    __syncthreads(); // previous compute done reading LDS
    splitWrite8(Ah, Al, off0, ra0, ra1);
    splitWrite8(Ah, Al, off1, ra2, ra3);
    splitWrite8(Bh, Bl, off0, rb0, rb1);
    splitWrite8(Bh, Bl, off1, rb2, rb3);
    __syncthreads(); // staging visible
    if (k0 + 32 < 1024) { // prefetch next tile; latency hides under MFMAs
      const float *an = aSrc + k0 + 32, *bn2 = bSrc + k0 + 32;
      ra0 = *(const f32x4 *)(an);      ra1 = *(const f32x4 *)(an + 4);
      ra2 = *(const f32x4 *)(an + 8);  ra3 = *(const f32x4 *)(an + 12);
      rb0 = *(const f32x4 *)(bn2);     rb1 = *(const f32x4 *)(bn2 + 4);
      rb2 = *(const f32x4 *)(bn2 + 8); rb3 = *(const f32x4 *)(bn2 + 12);
    }

    u16x8 afh[4], afl[4], bfh[4], bfl[4];
#pragma unroll
    for (int mf = 0; mf < 4; ++mf) {
      int r = wr * 64 + mf * 16 + l16;
      uint32_t off = r * 80 + g * 16;
      afh[mf] = *(const u16x8 *)((const char *)Ah + off);
      afl[mf] = *(const u16x8 *)((const char *)Al + off);
    }
#pragma unroll
    for (int nf = 0; nf < 4; ++nf) {
      int r = wc * 64 + nf * 16 + l16;
      uint32_t off = r * 80 + g * 16;
      bfh[nf] = *(const u16x8 *)((const char *)Bh + off);
      bfl[nf] = *(const u16x8 *)((const char *)Bl + off);
    }
#pragma unroll
    for (int mf = 0; mf < 4; ++mf)
#pragma unroll
      for (int nf = 0; nf < 4; ++nf) {
        acc[mf][nf] = mfma16(afh[mf], bfh[nf], acc[mf][nf]);
        acc[mf][nf] = mfma16(afh[mf], bfl[nf], acc[mf][nf]);
        acc[mf][nf] = mfma16(afl[mf], bfh[nf], acc[mf][nf]);
      }
  }

#pragma unroll
  for (int nf = 0; nf < 4; ++nf) {
    int col = bn * 128 + wc * 64 + nf * 16 + l16;
    float f = usefv ? fv[col] : 1.0f;
#pragma unroll
    for (int mf = 0; mf < 4; ++mf) {
      int row0 = bm * 128 + wr * 64 + mf * 16 + g * 4;
#pragma unroll
      for (int q = 0; q < 4; ++q) {
        float v = acc[mf][nf][q];
        v = (v > 0.f ? v : 0.f) * f;
        u16 hh, ll;
        split2(v, hh, ll);
        size_t idx = (size_t)(row0 + q) * 1024 + col;
        outh[idx] = hh;
        outl[idx] = ll;
      }
    }
  }
}

// ---------------- fused flash attention per (i-tile, level, batch) ----------
// 4 waves x 16 Q rows; K-tile = 32; pre-split hi/lo keys; T14 reg prefetch.
__global__ __launch_bounds__(256, 2) void attn_kernel(
    const u16 *__restrict__ x1kh, const u16 *__restrict__ x1kl,
    const u16 *__restrict__ x2kh, const u16 *__restrict__ x2kl,
    const u16 *__restrict__ vT, const float *__restrict__ bias,
    float *__restrict__ out) {
  __shared__ u16 K2h[32 * 256], K2l[32 * 256]; // 16KB each, 16B-gran XOR swz
  __shared__ u16 VTs[256 * 32];                // 16KB, 16B-gran XOR swz
  __shared__ float biasS[1024];
  __shared__ u16 P[4][16 * 36]; // per-wave P tile, row stride 72B (padded)

  const int t = threadIdx.x;
  const int lane = t & 63, wid = t >> 6;
  const int l16 = lane & 15, g = lane >> 4;
  const int it = blockIdx.x, m = blockIdx.y, b = blockIdx.z;

  for (int j = t; j < 1024; j += 256) biasS[j] = bias[b * 1024 + j];

  // Q hoist (pre-split): A-frag rows = l16, k = dk*32 + g*8 + e
  const int qrow = it * 64 + wid * 16 + l16;
  const u16 *qh = x1kh + ((size_t)b * 1024 + qrow) * 1024 + m * 256;
  const u16 *ql = x1kl + ((size_t)b * 1024 + qrow) * 1024 + m * 256;
  u16x8 Qh[8], Ql[8];
#pragma unroll
  for (int dk = 0; dk < 8; ++dk) {
    Qh[dk] = *(const u16x8 *)(qh + dk * 32 + g * 8);
    Ql[dk] = *(const u16x8 *)(ql + dk * 32 + g * 8);
  }

  f32x4 acc[16] = {};
  float mrow[4] = {-1e30f, -1e30f, -1e30f, -1e30f};
  float lrow[4] = {0.f, 0.f, 0.f, 0.f};

  // staging geometry
  const int sj = t >> 3, sck = (t & 7) * 32; // K: 8 thr/row, 32 u16 each
  const u16 *khsrc = x2kh + ((size_t)b * 1024 + sj) * 1024 + m * 256 + sck;
  const u16 *klsrc = x2kl + ((size_t)b * 1024 + sj) * 1024 + m * 256 + sck;
  const u16 *vtsrc = vT + ((size_t)((b * 4 + m) * 256 + t)) * 1024; // row=t
  uint32_t koff[4], voff[4];
#pragma unroll
  for (int q = 0; q < 4; ++q) {
    koff[q] = sj * 512 + ((((t & 7) * 64) + q * 16) ^ ((sj & 7) << 4));
    voff[q] = t * 64 + ((q * 16) ^ ((t & 3) << 4));
  }

  u16x8 pk_h[4], pk_l[4], pv[4];
#pragma unroll
  for (int q = 0; q < 4; ++q) {
    pk_h[q] = *(const u16x8 *)(khsrc + q * 8);
    pk_l[q] = *(const u16x8 *)(klsrc + q * 8);
    pv[q] = *(const u16x8 *)(vtsrc + q * 8);
  }

  for (int jt = 0; jt < 32; ++jt) {
    const int j0 = jt * 32;
    __syncthreads(); // prev compute done reading LDS
#pragma unroll
    for (int q = 0; q < 4; ++q) {
      *(u16x8 *)((char *)K2h + koff[q]) = pk_h[q];
      *(u16x8 *)((char *)K2l + koff[q]) = pk_l[q];
      *(u16x8 *)((char *)VTs + voff[q]) = pv[q];
    }
    __syncthreads(); // staging visible
    if (jt < 31) { // prefetch next tile (latency hides under compute)
      const u16 *kh2 = khsrc + (size_t)(jt + 1) * 32 * 1024;
      const u16 *kl2 = klsrc + (size_t)(jt + 1) * 32 * 1024;
      const u16 *vt2 = vtsrc + (jt + 1) * 32;
#pragma unroll
      for (int q = 0; q < 4; ++q) {
        pk_h[q] = *(const u16x8 *)(kh2 + q * 8);
        pk_l[q] = *(const u16x8 *)(kl2 + q * 8);
        pv[q] = *(const u16x8 *)(vt2 + q * 8);
      }
    }

    // QK^T (hi/lo, 48 MFMA): rows i=g*4+r, cols j=l16 (+16)
    f32x4 s0 = {0.f, 0.f, 0.f, 0.f}, s1 = {0.f, 0.f, 0.f, 0.f};
    __builtin_amdgcn_s_setprio(1);
    {
      const int j = l16;
      const uint32_t kxo = ((j & 7) << 4);
      const char *rowH = (const char *)K2h + j * 512;
      const char *rowL = (const char *)K2l + j * 512;
#pragma unroll
      for (int dk = 0; dk < 8; ++dk) {
        uint32_t off = (uint32_t)(dk * 64 + g * 16) ^ kxo;
        u16x8 kh = *(const u16x8 *)(rowH + off);
        u16x8 kl = *(const u16x8 *)(rowL + off);
        s0 = mfma16(Qh[dk], kh, s0);
        s0 = mfma16(Qh[dk], kl, s0);
        s0 = mfma16(Ql[dk], kh, s0);
      }
    }
    {
      const int j = 16 + l16;
      const uint32_t kxo = ((j & 7) << 4);
      const char *rowH = (const char *)K2h + j * 512;
      const char *rowL = (const char *)K2l + j * 512;
#pragma unroll
      for (int dk = 0; dk < 8; ++dk) {
        uint32_t off = (uint32_t)(dk * 64 + g * 16) ^ kxo;
        u16x8 kh = *(const u16x8 *)(rowH + off);
        u16x8 kl = *(const u16x8 *)(rowL + off);
        s1 = mfma16(Qh[dk], kh, s1);
        s1 = mfma16(Qh[dk], kl, s1);
        s1 = mfma16(Ql[dk], kh, s1);
      }
    }
    __builtin_amdgcn_s_setprio(0);

    // online softmax (rows replicated across 16 lanes of each g-group)
    float sv[2][4];
    const float bj0 = biasS[j0 + l16], bj1 = biasS[j0 + 16 + l16];
#pragma unroll
    for (int r = 0; r < 4; ++r) { sv[0][r] = s0[r] + bj0; sv[1][r] = s1[r] + bj1; }
    float tm[4];
#pragma unroll
    for (int r = 0; r < 4; ++r) tm[r] = fmaxf(sv[0][r], sv[1][r]);
#pragma unroll
    for (int d = 1; d < 16; d <<= 1)
#pragma unroll
      for (int r = 0; r < 4; ++r) tm[r] = fmaxf(tm[r], __shfl_xor(tm[r], d, 64));
    float sc[4];
#pragma unroll
    for (int r = 0; r < 4; ++r) {
      float nm = fmaxf(mrow[r], tm[r]);
      sc[r] = exp2f((mrow[r] - nm) * L2E);
      mrow[r] = nm;
    }
    float p[2][4], rs[4];
#pragma unroll
    for (int r = 0; r < 4; ++r) {
      p[0][r] = exp2f((sv[0][r] - mrow[r]) * L2E);
      p[1][r] = exp2f((sv[1][r] - mrow[r]) * L2E);
      rs[r] = p[0][r] + p[1][r];
    }
#pragma unroll
    for (int d = 1; d < 16; d <<= 1)
#pragma unroll
      for (int r = 0; r < 4; ++r) rs[r] += __shfl_xor(rs[r], d, 64);
#pragma unroll
    for (int r = 0; r < 4; ++r) lrow[r] = lrow[r] * sc[r] + rs[r];
#pragma unroll
    for (int nf = 0; nf < 16; ++nf)
#pragma unroll
      for (int r = 0; r < 4; ++r) acc[nf][r] *= sc[r];

    // P -> per-wave LDS (bf16, stride 36 u16), then PV
    u16 *Pw = &P[wid][0];
#pragma unroll
    for (int sub = 0; sub < 2; ++sub)
#pragma unroll
      for (int r = 0; r < 4; ++r) {
        int il = g * 4 + r, jl = sub * 16 + l16;
        Pw[il * 36 + jl] = f2bf(p[sub][r]);
      }
    u16x8 pa;
    {
      const u16 *pp = Pw + l16 * 36 + g * 8;
      u16x4 a0 = *(const u16x4 *)(pp);
      u16x4 a1 = *(const u16x4 *)(pp + 4);
      pa = __builtin_shufflevector(a0, a1, 0, 1, 2, 3, 4, 5, 6, 7);
    }
    __builtin_amdgcn_s_setprio(1);
#pragma unroll
    for (int nf = 0; nf < 16; ++nf) {
      int dd = nf * 16 + l16;
      uint32_t off = dd * 64 + ((g * 16) ^ ((dd & 3) << 4));
      u16x8 bb = *(const u16x8 *)((const char *)VTs + off);
      acc[nf] = mfma16(pa, bb, acc[nf]);
    }
    __builtin_amdgcn_s_setprio(0);
  }

  float inv[4];
#pragma unroll
  for (int r = 0; r < 4; ++r) inv[r] = 1.0f / lrow[r];
#pragma unroll
  for (int nf = 0; nf < 16; ++nf) {
    int col = m * 256 + nf * 16 + l16;
#pragma unroll
    for (int r = 0; r < 4; ++r) {
      int row = it * 64 + wid * 16 + g * 4 + r;
      out[((size_t)b * 1024 + row) * 1024 + col] = acc[nf][r] * inv[r];
    }
  }
}

// ---------------- launch ----------------------------------------------------
extern "C" void kernel_launch(void *const *d_in, const int *in_sizes, int n_in,
                              void *d_out, int out_size, void *d_ws,
                              size_t ws_size, hipStream_t stream) {
  const float *x1_att = (const float *)d_in[0];
  const float *x2_att = (const float *)d_in[1];
  const float *x2 = (const float *)d_in[2];
  const unsigned char *mask = (const unsigned char *)d_in[3];
  const float *W = (const float *)d_in[4];
  const float *fv = (const float *)d_in[5];
  float *out = (float *)d_out;

  char *ws = (char *)d_ws;
  u16 *x1kh = (u16 *)ws;                    // 8192*1024*2 = 16777216 B
  u16 *x1kl = (u16 *)(ws + 16777216);       // 16777216 B
  u16 *x2kh = (u16 *)(ws + 33554432);       // 16777216 B
  u16 *x2kl = (u16 *)(ws + 50331648);       // 16777216 B
  u16 *vT = (u16 *)(ws + 67108864);         // 16777216 B
  float *bias = (float *)(ws + 83886080);   // 32768 B

  prep_mask_kernel<<<dim3(1), dim3(256), 0, stream>>>(mask, bias);
  transpose_v_kernel<<<dim3(32, 32, 8), dim3(256), 0, stream>>>(x2, vT);
  proj_kernel<<<dim3(64, 8), dim3(256), 0, stream>>>(x1_att, W, fv, x1kh, x1kl, 0);
  proj_kernel<<<dim3(64, 8), dim3(256), 0, stream>>>(x2_att, W, fv, x2kh, x2kl, 1);
  attn_kernel<<<dim3(16, 4, 8), dim3(256), 0, stream>>>(x1kh, x1kl, x2kh, x2kl,
                                                        vT, bias, out);
}